// Round 1
// baseline (5305.119 us; speedup 1.0000x reference)
//
#include <hip/hip_runtime.h>

// Stacked 2-layer tanh RNN, SEQ=512, B=64, IN=H=1024.
// Persistent pipelined kernel: 64 L0-WGs + 64 L1-WGs, flag sync via LLC
// (sc0 sc1 loads/stores bypass the non-coherent per-XCD L2s).
// Weights held in VGPRs (16 bf16x8 frags per wave), bf16 MFMA 16x16x32,
// fp32 accumulate, cross-wave K-reduce in LDS, tanh in f32.

typedef unsigned short ushort_t;
typedef unsigned int uint32;
typedef __attribute__((ext_vector_type(2))) unsigned int u32x2;
typedef __attribute__((ext_vector_type(4))) unsigned int u32x4;
typedef __attribute__((ext_vector_type(2))) float f32x2;
typedef __attribute__((ext_vector_type(4))) float f32x4;
typedef __attribute__((ext_vector_type(8))) __bf16 bfrag;

__device__ __forceinline__ uint32 bf16rne(float f) {
  uint32 u = __builtin_bit_cast(uint32, f);
  return (u + 0x7fffu + ((u >> 16) & 1u)) >> 16;
}

__device__ __forceinline__ f32x4 mfma_bf16(u32x4 a, u32x4 b, f32x4 c) {
  return __builtin_amdgcn_mfma_f32_16x16x32_bf16(
      __builtin_bit_cast(bfrag, a), __builtin_bit_cast(bfrag, b), c, 0, 0, 0);
}

// Coherent (LLC) flag poll: load bypassing L1/L2, self-draining.
__device__ __forceinline__ void spin_ge(const int* p, int tgt) {
  int v;
  do {
    asm volatile("global_load_dword %0, %1, off sc0 sc1\n\ts_waitcnt vmcnt(0)"
                 : "=v"(v) : "v"(p) : "memory");
  } while (v < tgt);
}

// Issue 16 coherent 16B loads (one MFMA A-frag each), no wait.
__device__ __forceinline__ void load_sc16(u32x4 (&dst)[16], const ushort_t* base) {
#pragma unroll
  for (int kk = 0; kk < 16; ++kk)
    asm volatile("global_load_dwordx4 %0, %1, off sc0 sc1"
                 : "=v"(dst[kk]) : "v"(base + 32 * kk) : "memory");
}

// ---------------- prep: f32 -> bf16 conversions + flag zeroing ----------------
__global__ __launch_bounds__(256) void rnn_prep(
    const float* __restrict__ Xt, const float* __restrict__ W0,
    const float* __restrict__ W1, ushort_t* __restrict__ Xbf,
    ushort_t* __restrict__ W0bf, ushort_t* __restrict__ W1bf,
    int* __restrict__ flags) {
  const long nX = 512L * 64 * 1024 / 4;  // quads
  const long nW = 1024L * 2048 / 4;
  const long total = nX + 2 * nW;
  long stride = (long)gridDim.x * blockDim.x;
  for (long v = (long)blockIdx.x * blockDim.x + threadIdx.x; v < total; v += stride) {
    const float* src;
    ushort_t* dst;
    long off;
    if (v < nX) { src = Xt; dst = Xbf; off = v; }
    else if (v < nX + nW) { src = W0; dst = W0bf; off = v - nX; }
    else { src = W1; dst = W1bf; off = v - nX - nW; }
    f32x4 f = *(const f32x4*)(src + off * 4);
    u32x2 o;
    o.x = bf16rne(f.x) | (bf16rne(f.y) << 16);
    o.y = bf16rne(f.z) | (bf16rne(f.w) << 16);
    *(u32x2*)(dst + off * 4) = o;
  }
  int t0 = blockIdx.x * blockDim.x + threadIdx.x;
  if (t0 < 128) {
    int z = 0;
    asm volatile("global_store_dword %0, %1, off sc0 sc1\n\ts_waitcnt vmcnt(0)"
                 :: "v"(flags + t0), "v"(z) : "memory");
  }
}

// ---------------- main persistent pipelined RNN kernel ----------------
// grid = 128 blocks x 512 threads. Block g<64: layer0 features [16g,16g+16);
// g>=64: layer1. 8 waves: kq=wave&3 K-quarter (512 wide), mh=wave>>2 m-half.
__global__ __launch_bounds__(512) void rnn_main(
    const ushort_t* __restrict__ Xbf,   // [512][64][1024] bf16
    const ushort_t* __restrict__ W0bf,  // [1024][2048] bf16
    const ushort_t* __restrict__ W1bf,  // [1024][2048] bf16
    const float* __restrict__ b0, const float* __restrict__ b1,
    ushort_t* h0buf,  // [2][64][1024] bf16 (double buffered)
    ushort_t* h1buf,  // [2][64][1024] bf16
    float* __restrict__ Y,  // [512][64][1024] f32 (d_out)
    int* flag0, int* flag1) {
  __shared__ float part[8][32][20];  // [wave][m-local][16f + pad4]

  const int tid = threadIdx.x;
  const int wave = tid >> 6;
  const int lane = tid & 63;
  const int ln15 = lane & 15;
  const int lq = lane >> 4;
  const int kq = wave & 3;
  const int mh = wave >> 2;
  const int g = blockIdx.x;
  const bool isL1 = (g >= 64);
  const int gl = isL1 ? g - 64 : g;
  const int F0 = gl * 16;
  const int koff = (kq & 1) * 512;   // k-offset within the 1024-wide source
  const int mt0 = mh * 2;            // first of this wave's two 16-row m-tiles
  const bool hcons = (kq >= 2);      // waves consuming recurrent state

  // Load this wave's weight slice into registers: 16 frags = 64 VGPRs.
  const ushort_t* Wsrc = isL1 ? W1bf : W0bf;
  u32x4 bw[16];
  {
    const ushort_t* wp = Wsrc + (size_t)(F0 + ln15) * 2048 + kq * 512 + lq * 8;
#pragma unroll
    for (int kk = 0; kk < 16; ++kk) bw[kk] = *(const u32x4*)(wp + kk * 32);
  }

  // Reduce-phase assignment: thread -> (batch rm, feature pair rf).
  const int rm = tid >> 3;
  const int rml = rm & 31;
  const int rmh4 = (rm >> 5) * 4;
  const int rf = (tid & 7) * 2;
  const float* bsrc = isL1 ? b1 : b0;
  const float bia0 = bsrc[F0 + rf];
  const float bia1 = bsrc[F0 + rf + 1];

  for (int t = 0; t < 512; ++t) {
    // ---- phase 1: flag waits (per-lane flag, divergent spin ok) ----
    if (!isL1) {
      if (hcons) { if (t >= 1) spin_ge(flag0 + lane, t); }          // h0(t-1) ready
      else if (wave == 0 && t >= 2) spin_ge(flag1 + lane, t - 1);   // h0-slot overwrite gate
    } else {
      if (!hcons) spin_ge(flag0 + lane, t + 1);                     // h0(t) ready
      else if (t >= 1) spin_ge(flag1 + lane, t);                    // h1(t-1) ready
    }

    // ---- phase 2: partial GEMM into fp32 accumulators ----
    f32x4 aA0 = {0.f, 0.f, 0.f, 0.f}, aB0 = aA0, aA1 = aA0, aB1 = aA0;
    const bool active = (t >= 1) || !hcons;
    if (active) {
      if (!isL1 && !hcons) {
        // X path: plain cached loads (L2-dedup across WGs of an XCD).
        const ushort_t* ax = Xbf + (size_t)t * 65536 + koff + lq * 8;
        const ushort_t* p0 = ax + (size_t)(mt0 * 16 + ln15) * 1024;
        const ushort_t* p1 = p0 + 16 * 1024;
#pragma unroll
        for (int kk = 0; kk < 16; ++kk) {
          u32x4 a0 = *(const u32x4*)(p0 + kk * 32);
          u32x4 a1 = *(const u32x4*)(p1 + kk * 32);
          if (kk & 1) { aB0 = mfma_bf16(a0, bw[kk], aB0); aB1 = mfma_bf16(a1, bw[kk], aB1); }
          else        { aA0 = mfma_bf16(a0, bw[kk], aA0); aA1 = mfma_bf16(a1, bw[kk], aA1); }
        }
      } else {
        // recurrent-state path: coherent LLC loads.
        const ushort_t* hb;
        if (!isL1)       hb = h0buf + ((t - 1) & 1) * 65536;
        else if (!hcons) hb = h0buf + (t & 1) * 65536;
        else             hb = h1buf + ((t - 1) & 1) * 65536;
        const ushort_t* p0 = hb + (size_t)(mt0 * 16 + ln15) * 1024 + koff + lq * 8;
        const ushort_t* p1 = p0 + 16 * 1024;
        u32x4 fA[16], fB[16];
        load_sc16(fA, p0);
        load_sc16(fB, p1);
        asm volatile("s_waitcnt vmcnt(0)" ::: "memory");
        __builtin_amdgcn_sched_barrier(0);
#pragma unroll
        for (int kk = 0; kk < 16; ++kk) {
          if (kk & 1) { aB0 = mfma_bf16(fA[kk], bw[kk], aB0); aB1 = mfma_bf16(fB[kk], bw[kk], aB1); }
          else        { aA0 = mfma_bf16(fA[kk], bw[kk], aA0); aA1 = mfma_bf16(fB[kk], bw[kk], aA1); }
        }
      }
    }

    // ---- phase 3: dump partials to LDS ----
    {
      f32x4 s0 = aA0 + aB0, s1 = aA1 + aB1;
#pragma unroll
      for (int r = 0; r < 4; ++r) {
        part[wave][lq * 4 + r][ln15] = s0[r];
        part[wave][16 + lq * 4 + r][ln15] = s1[r];
      }
    }
    __syncthreads();

    // ---- phase 4: K-reduce over 4 kq-waves, bias, tanh, stores ----
    {
      float s0 = 0.f, s1 = 0.f;
#pragma unroll
      for (int w = 0; w < 4; ++w) {
        f32x2 v = *(const f32x2*)&part[rmh4 + w][rml][rf];
        s0 += v.x; s1 += v.y;
      }
      float y0 = tanhf(s0 + bia0);
      float y1 = tanhf(s1 + bia1);
      uint32 hp = bf16rne(y0) | (bf16rne(y1) << 16);
      ushort_t* hd = (isL1 ? h1buf : h0buf) + (t & 1) * 65536 + rm * 1024 + F0 + rf;
      asm volatile("global_store_dword %0, %1, off sc0 sc1" :: "v"(hd), "v"(hp) : "memory");
      if (isL1) {
        f32x2 yv = {y0, y1};
        *(f32x2*)(Y + ((size_t)t * 64 + rm) * 1024 + F0 + rf) = yv;
      }
      asm volatile("s_waitcnt vmcnt(0)" ::: "memory");  // all stores at LLC/retired
    }
    __syncthreads();
    if (tid == 0) {
      int* fp = (isL1 ? flag1 : flag0) + gl;
      int val = t + 1;
      asm volatile("global_store_dword %0, %1, off sc0 sc1\n\ts_waitcnt vmcnt(0)"
                   :: "v"(fp), "v"(val) : "memory");
    }
  }
}

extern "C" void kernel_launch(void* const* d_in, const int* in_sizes, int n_in,
                              void* d_out, int out_size, void* d_ws, size_t ws_size,
                              hipStream_t stream) {
  const float* Xt = (const float*)d_in[0];
  const float* W0 = (const float*)d_in[1];
  const float* b0 = (const float*)d_in[2];
  const float* W1 = (const float*)d_in[3];
  const float* b1 = (const float*)d_in[4];
  float* Y = (float*)d_out;

  ushort_t* Xbf = (ushort_t*)d_ws;                          // 67,108,864 B
  ushort_t* W0bf = Xbf + (size_t)512 * 64 * 1024;           // 4,194,304 B
  ushort_t* W1bf = W0bf + (size_t)1024 * 2048;              // 4,194,304 B
  ushort_t* h0buf = W1bf + (size_t)1024 * 2048;             // 262,144 B
  ushort_t* h1buf = h0buf + (size_t)2 * 64 * 1024;          // 262,144 B
  int* flags = (int*)(h1buf + (size_t)2 * 64 * 1024);       // 512 B

  rnn_prep<<<2048, 256, 0, stream>>>(Xt, W0, W1, Xbf, W0bf, W1bf, flags);
  rnn_main<<<128, 512, 0, stream>>>(Xbf, W0bf, W1bf, b0, b1, h0buf, h1buf, Y,
                                    flags, flags + 64);
}